// Round 7
// baseline (672.622 us; speedup 1.0000x reference)
//
#include <hip/hip_runtime.h>
#include <math.h>

#define NN 27
#define HID 128
#define SITERS 20
#define CHS 40           // H-chunk row stride in f16 (80 B = 16B-aligned, bank-spread)

typedef float    v4    __attribute__((ext_vector_type(4)));
typedef _Float16 f16x8 __attribute__((ext_vector_type(8)));

// ---------------- Kernel 0: pre-swizzle W2 / protos into f16 MFMA fragment order ----------------
// B-frag (16x16x32): lane l holds B[k=kt*32+(l>>4)*8+j][n=nt*16+(l&15)], j=0..7 -> one 16B load/lane.
// A-frag:            lane l holds A[m=mt*16+(l&15)][k=kt*32+(l>>4)*8+j]
__global__ void k0_prep(const float* __restrict__ W2, const float* __restrict__ protos,
                        _Float16* __restrict__ Bsw, _Float16* __restrict__ Asw)
{
    int t0 = blockIdx.x * 256 + threadIdx.x;
    for (int idx = t0; idx < 4*8*64*8; idx += 8*256) {       // W2: kt(4) x nt(8) x lane x 8
        int j = idx & 7, l = (idx >> 3) & 63, nt = (idx >> 9) & 7, kt = idx >> 12;
        int k = kt*32 + (l >> 4)*8 + j, n = nt*16 + (l & 15);
        Bsw[idx] = (_Float16)W2[k*HID + n];
    }
    for (int idx = t0; idx < 2*4*64*8; idx += 8*256) {       // protos: mt(2) x kt(4) x lane x 8
        int j = idx & 7, l = (idx >> 3) & 63, kt = (idx >> 9) & 3, mt = idx >> 11;
        int k = kt*32 + (l >> 4)*8 + j, mm = mt*16 + (l & 15);
        Asw[idx] = (mm < NN) ? (_Float16)protos[mm*HID + k] : (_Float16)0.0f;
    }
}

// ---------------- Kernel 1: ONE WAVE PER MATRIX, 2 waves/block, LDS-slim, barrier-free ---------
// History: R6 MFMA rewrite; R7 LDS union; R8 Sinkhorn fusion; R9 despill; R10 register Sinkhorn;
// R11 rcpf; R12 one-wave-per-matrix (409us, occupancy 43.5% -- LDS 9216B caps ~16 waves/CU).
// R13 (this round): LDS 9216 -> ~3.4KB/matrix so occupancy is VGPR-bound (~24 waves/CU):
// - af[mt][kt] computed DIRECTLY in regs from sFeat (LDS broadcast) x W1 (v4, L1-broadcast):
//   h1 never touches LDS. Bit-exact FMA nesting (init=b1, q=3..0). Pad feat rows zeroed;
//   all pad-row/col garbage is masked in P6 (explicit 0 stores, no NaN paths).
// - H transpose chunked: pass2 fused with P5 per kt2 (recompute 2 nt-tiles -> LN2 -> 32x32 f16
//   chunk -> wave_barrier -> B-frags + 4 MFMA). 8704B sH -> 2560B chunk aliased over dead sA.
// - 128-thread blocks = 2 independent waves (2 matrices), ZERO syncthreads; WG-slot limits
//   can't bind. launch_bounds(128,6): VGPR cap 84 (est peak ~84 in fused pass2).
__global__ __launch_bounds__(128, 6) void k1_mlp(
    const float* __restrict__ A, const float* __restrict__ m,
    const float* __restrict__ tau_r,
    const float* __restrict__ ln1g, const float* __restrict__ ln1b,
    const float* __restrict__ W1, const float* __restrict__ b1,
    const float* __restrict__ b2,
    const float* __restrict__ ln2g, const float* __restrict__ ln2b,
    const _Float16* __restrict__ Bsw, const _Float16* __restrict__ Asw,
    float* __restrict__ out, int Btot)
{
    __shared__ __align__(16) float sU[2][736];       // per-wave union: sA(729 f32) / chunk(1280 f16)
    __shared__ __align__(16) float sFeat2[2][132];   // 32 rows x 4 (pads zeroed)

    const int tid = threadIdx.x;
    const int w   = tid >> 6, l = tid & 63;
    const int b   = blockIdx.x * 2 + w;
    if (b >= Btot) return;                           // whole wave exits; no block sync anywhere
    const int c = l & 15, g = l >> 4;

    float*    sA    = sU[w];
    _Float16* chunk = (_Float16*)sU[w];
    float*    sFeat = sFeat2[w];
    const float* Ab = A + (size_t)b * (NN * NN);

    // ---- P0: stage A (per-wave) ----
    for (int i = l; i < NN * NN; i += 64) sA[i] = Ab[i];
    __builtin_amdgcn_wave_barrier();

    // ---- P1: features [log1p(rowsum), top1_offdiag, top2_offdiag, m] + LN1; zero pad rows ----
    if (l < NN) {
        const int n = l;
        float sum = 0.f, m1 = -1e30f, m2 = -1e30f;
        #pragma unroll
        for (int j = 0; j < NN; ++j) {
            float a = sA[n * NN + j];
            sum += a;
            float v = (j == n) ? 0.f : a;
            float nm1 = fmaxf(m1, v);
            m2 = fmaxf(m2, fminf(m1, v));
            m1 = nm1;
        }
        float f0 = log1pf(sum), f1 = m1, f2 = m2, f3 = m[(size_t)b * NN + n];
        float mu = 0.25f * (f0 + f1 + f2 + f3);
        float d0 = f0 - mu, d1 = f1 - mu, d2 = f2 - mu, d3 = f3 - mu;
        float var = 0.25f * (d0*d0 + d1*d1 + d2*d2 + d3*d3);
        float rs  = rsqrtf(var + 1e-5f);
        sFeat[n*4 + 0] = d0 * rs * ln1g[0] + ln1b[0];
        sFeat[n*4 + 1] = d1 * rs * ln1g[1] + ln1b[1];
        sFeat[n*4 + 2] = d2 * rs * ln1g[2] + ln1b[2];
        sFeat[n*4 + 3] = d3 * rs * ln1g[3] + ln1b[3];
    } else if (l < 32) {
        sFeat[l*4 + 0] = 0.f; sFeat[l*4 + 1] = 0.f;
        sFeat[l*4 + 2] = 0.f; sFeat[l*4 + 3] = 0.f;
    }
    __builtin_amdgcn_wave_barrier();

    // ---- P2': A-fragments of h1 computed DIRECTLY in registers (no LDS h1). ----
    // af[mt][kt][j] = relu(b1[col] + sum_q feat[mt*16+c][q]*W1[q][col]), col = kt*32+g*8+j.
    // FMA nesting matches old P2 exactly: h = b; h = fma(f3,w3,h); ... ; h = fma(f0,w0,h).
    v4 fr0 = *(const v4*)&sFeat[(0*16 + c) * 4];
    v4 fr1 = *(const v4*)&sFeat[(1*16 + c) * 4];
    f16x8 af[2][4];
    #pragma unroll
    for (int kt = 0; kt < 4; ++kt) {
        const int c0 = kt*32 + g*8;
        v4 bA = *(const v4*)&b1[c0];
        v4 bB = *(const v4*)&b1[c0 + 4];
        float h0[8], h1v[8];
        #pragma unroll
        for (int j = 0; j < 4; ++j) {
            h0[j] = bA[j];  h0[4+j] = bB[j];
            h1v[j] = bA[j]; h1v[4+j] = bB[j];
        }
        #pragma unroll
        for (int q = 3; q >= 0; --q) {
            v4 wA = *(const v4*)&W1[q*HID + c0];
            v4 wB = *(const v4*)&W1[q*HID + c0 + 4];
            float fq0 = fr0[q], fq1 = fr1[q];
            #pragma unroll
            for (int j = 0; j < 4; ++j) {
                h0[j]    = fmaf(fq0, wA[j], h0[j]);
                h0[4+j]  = fmaf(fq0, wB[j], h0[4+j]);
                h1v[j]   = fmaf(fq1, wA[j], h1v[j]);
                h1v[4+j] = fmaf(fq1, wB[j], h1v[4+j]);
            }
        }
        f16x8 v0, v1;
        #pragma unroll
        for (int j = 0; j < 8; ++j) {
            v0[j] = (_Float16)fmaxf(h0[j],  0.f);
            v1[j] = (_Float16)fmaxf(h1v[j], 0.f);
        }
        af[0][kt] = v0;
        af[1][kt] = v1;
    }

    // ---- P3 pass 1: GEMM2 LN2 stats only (tiles discarded; despill-proven structure) ----
    const f16x8* Bv = (const f16x8*)Bsw;
    float s4[2][4]  = {{0.f,0.f,0.f,0.f},{0.f,0.f,0.f,0.f}};
    float ss4[2][4] = {{0.f,0.f,0.f,0.f},{0.f,0.f,0.f,0.f}};
    #pragma unroll 1
    for (int nt = 0; nt < 8; ++nt) {
        f16x8 bf[4];
        #pragma unroll
        for (int kt = 0; kt < 4; ++kt) bf[kt] = Bv[(kt*8 + nt)*64 + l];
        float b2v = b2[nt*16 + c];
        #pragma unroll
        for (int mt = 0; mt < 2; ++mt) {
            v4 a = (v4)(0.f);
            #pragma unroll
            for (int kt = 0; kt < 4; ++kt)
                a = __builtin_amdgcn_mfma_f32_16x16x32_f16(af[mt][kt], bf[kt], a, 0, 0, 0);
            #pragma unroll
            for (int r = 0; r < 4; ++r) {
                float v = a[r] + b2v;
                s4[mt][r] += v; ss4[mt][r] += v * v;
            }
        }
    }
    float muv[2][4], rsv[2][4];
    #pragma unroll
    for (int mt = 0; mt < 2; ++mt)
        #pragma unroll
        for (int r = 0; r < 4; ++r) {
            #pragma unroll
            for (int mask = 1; mask <= 8; mask <<= 1) {
                s4[mt][r]  += __shfl_xor(s4[mt][r],  mask);
                ss4[mt][r] += __shfl_xor(ss4[mt][r], mask);
            }
            float mu  = s4[mt][r] * (1.0f / HID);
            float var = ss4[mt][r] * (1.0f / HID) - mu * mu;
            muv[mt][r] = mu;
            rsv[mt][r] = rsqrtf(var + 1e-5f);
        }

    // ---- P3 pass 2 FUSED with P5: per kt2, recompute 2 nt-tiles -> LN2 -> 32x32 chunk ->
    //      consume as scores B-frags (chunk aliases dead sA; intra-wave DS is in-order). ----
    const f16x8* Av = (const f16x8*)Asw;
    v4 acc2[2][2];
    acc2[0][0] = (v4)(0.f); acc2[0][1] = (v4)(0.f);
    acc2[1][0] = (v4)(0.f); acc2[1][1] = (v4)(0.f);
    #pragma unroll 1
    for (int kt2 = 0; kt2 < 4; ++kt2) {
        #pragma unroll
        for (int h = 0; h < 2; ++h) {
            int nt = kt2*2 + h;
            f16x8 bf[4];
            #pragma unroll
            for (int kt = 0; kt < 4; ++kt) bf[kt] = Bv[(kt*8 + nt)*64 + l];
            int col = nt*16 + c;
            float b2v = b2[col], g2 = ln2g[col], bb = ln2b[col];
            #pragma unroll
            for (int mt = 0; mt < 2; ++mt) {
                v4 a = (v4)(0.f);
                #pragma unroll
                for (int kt = 0; kt < 4; ++kt)
                    a = __builtin_amdgcn_mfma_f32_16x16x32_f16(af[mt][kt], bf[kt], a, 0, 0, 0);
                #pragma unroll
                for (int r = 0; r < 4; ++r) {
                    float hv = (a[r] + b2v - muv[mt][r]) * rsv[mt][r] * g2 + bb;
                    chunk[(mt*16 + 4*g + r) * CHS + h*16 + c] = (_Float16)hv;
                }
            }
        }
        __builtin_amdgcn_wave_barrier();    // chunk writes ordered before reads (compiler fence)
        f16x8 b0  = *(const f16x8*)&chunk[(c)      * CHS + g*8];
        f16x8 b1f = *(const f16x8*)&chunk[(16 + c) * CHS + g*8];
        f16x8 pa0 = Av[(0*4 + kt2)*64 + l];
        f16x8 pa1 = Av[(1*4 + kt2)*64 + l];
        acc2[0][0] = __builtin_amdgcn_mfma_f32_16x16x32_f16(pa0, b0,  acc2[0][0], 0, 0, 0);
        acc2[0][1] = __builtin_amdgcn_mfma_f32_16x16x32_f16(pa0, b1f, acc2[0][1], 0, 0, 0);
        acc2[1][0] = __builtin_amdgcn_mfma_f32_16x16x32_f16(pa1, b0,  acc2[1][0], 0, 0, 0);
        acc2[1][1] = __builtin_amdgcn_mfma_f32_16x16x32_f16(pa1, b1f, acc2[1][1], 0, 0, 0);
        __builtin_amdgcn_wave_barrier();    // reads ordered before next iter's writes
    }

    // ---- P6: P = exp(score/tau) in registers. i = mt*16+4g+r, j0 = c, j1 = 16+c ----
    float p[2][2][4];
    float rowm1[4], rowp1[4];
    #pragma unroll
    for (int r = 0; r < 4; ++r) {
        rowm1[r] = ((16 + 4*g + r) < NN) ? 1.f : 0.f;
        rowp1[r] = 1.f - rowm1[r];
    }
    const float colm1 = ((16 + c) < NN) ? 1.f : 0.f;
    const float colp1 = 1.f - colm1;
    {
        const float inv_tau = 1.0f / tau_r[0];
        #pragma unroll
        for (int r = 0; r < 4; ++r) {
            p[0][0][r] = __expf(acc2[0][0][r] * inv_tau);
            p[0][1][r] = (colm1 != 0.f) ? __expf(acc2[0][1][r] * inv_tau) : 0.f;
            bool iok = (16 + 4*g + r) < NN;
            p[1][0][r] = iok ? __expf(acc2[1][0][r] * inv_tau) : 0.f;
            p[1][1][r] = (iok && colm1 != 0.f) ? __expf(acc2[1][1][r] * inv_tau) : 0.f;
        }
    }

    // ---- P7: 20-iter Sinkhorn, fully wave-local (shfl + rcpf only; no LDS, no barriers) ----
    for (int it = 0; it < SITERS; ++it) {
        #pragma unroll
        for (int r = 0; r < 4; ++r) {           // row normalize, mt=0 (always valid)
            float s = p[0][0][r] + p[0][1][r];
            s += __shfl_xor(s, 1);
            s += __shfl_xor(s, 2);
            s += __shfl_xor(s, 4);
            s += __shfl_xor(s, 8);
            float rho = __builtin_amdgcn_rcpf(s);
            p[0][0][r] *= rho;
            p[0][1][r] *= rho;
        }
        #pragma unroll
        for (int r = 0; r < 4; ++r) {           // row normalize, mt=1 (pad rows stay exact 0)
            float s = p[1][0][r] + p[1][1][r];
            s += __shfl_xor(s, 1);
            s += __shfl_xor(s, 2);
            s += __shfl_xor(s, 4);
            s += __shfl_xor(s, 8);
            float rho = __builtin_amdgcn_rcpf(s + rowp1[r]) * rowm1[r];
            p[1][0][r] *= rho;
            p[1][1][r] *= rho;
        }
        // col normalize: sum over (mt,r) in-thread, then g-groups via shfl 16/32
        float t0 = ((p[0][0][0] + p[0][0][1]) + (p[0][0][2] + p[0][0][3]))
                 + ((p[1][0][0] + p[1][0][1]) + (p[1][0][2] + p[1][0][3]));
        float t1 = ((p[0][1][0] + p[0][1][1]) + (p[0][1][2] + p[0][1][3]))
                 + ((p[1][1][0] + p[1][1][1]) + (p[1][1][2] + p[1][1][3]));
        t0 += __shfl_xor(t0, 16);  t0 += __shfl_xor(t0, 32);
        t1 += __shfl_xor(t1, 16);  t1 += __shfl_xor(t1, 32);
        float rc0 = __builtin_amdgcn_rcpf(t0);
        float rc1 = __builtin_amdgcn_rcpf(t1 + colp1) * colm1;
        #pragma unroll
        for (int mt = 0; mt < 2; ++mt) {
            #pragma unroll
            for (int r = 0; r < 4; ++r) {
                p[mt][0][r] *= rc0;
                p[mt][1][r] *= rc1;
            }
        }
    }

    // ---- P8: store P straight from registers (16-lane contiguous runs) ----
    {
        float* ob = out + (size_t)b * (NN * NN);
        #pragma unroll
        for (int r = 0; r < 4; ++r) {
            int i = 4*g + r;
            ob[i * NN + c] = p[0][0][r];
            if ((16 + c) < NN) ob[i * NN + 16 + c] = p[0][1][r];
        }
        #pragma unroll
        for (int r = 0; r < 4; ++r) {
            int i = 16 + 4*g + r;
            if (i < NN) {
                ob[i * NN + c] = p[1][0][r];
                if ((16 + c) < NN) ob[i * NN + 16 + c] = p[1][1][r];
            }
        }
    }
}

extern "C" void kernel_launch(void* const* d_in, const int* in_sizes, int n_in,
                              void* d_out, int out_size, void* d_ws, size_t ws_size,
                              hipStream_t stream) {
    const float* A      = (const float*)d_in[0];
    const float* m      = (const float*)d_in[1];
    const float* tau_r  = (const float*)d_in[2];
    const float* ln1g   = (const float*)d_in[3];
    const float* ln1b   = (const float*)d_in[4];
    const float* W1     = (const float*)d_in[5];
    const float* b1     = (const float*)d_in[6];
    const float* W2     = (const float*)d_in[7];
    const float* b2     = (const float*)d_in[8];
    const float* ln2g   = (const float*)d_in[9];
    const float* ln2b   = (const float*)d_in[10];
    const float* protos = (const float*)d_in[11];
    float* out = (float*)d_out;

    const int B = in_sizes[0] / (NN * NN);

    _Float16* Bsw = (_Float16*)d_ws;                         // 16384 f16 = 32 KB
    _Float16* Asw = (_Float16*)((char*)d_ws + 32768);        //  4096 f16 =  8 KB

    k0_prep<<<8, 256, 0, stream>>>(W2, protos, Bsw, Asw);
    const int blocks1 = (B + 1) / 2;
    k1_mlp<<<blocks1, 128, 0, stream>>>(A, m, tau_r, ln1g, ln1b, W1, b1, b2,
                                        ln2g, ln2b, Bsw, Asw, out, B);
}

// Round 8
// 638.782 us; speedup vs baseline: 1.0530x; 1.0530x over previous
//
#include <hip/hip_runtime.h>
#include <math.h>

#define NN 27
#define HID 128
#define SITERS 20
#define CHF 36           // f32 chunk row stride (144 B: 16B-aligned, 2-way-bank-free writes)

typedef float    v4    __attribute__((ext_vector_type(4)));
typedef _Float16 f16x8 __attribute__((ext_vector_type(8)));

// ---------------- Kernel 0: pre-swizzle W2 / protos into f16 MFMA fragment order ----------------
// B-frag (16x16x32): lane l holds B[k=kt*32+(l>>4)*8+j][n=nt*16+(l&15)], j=0..7 -> one 16B load/lane.
// A-frag:            lane l holds A[m=mt*16+(l&15)][k=kt*32+(l>>4)*8+j]
__global__ void k0_prep(const float* __restrict__ W2, const float* __restrict__ protos,
                        _Float16* __restrict__ Bsw, _Float16* __restrict__ Asw)
{
    int t0 = blockIdx.x * 256 + threadIdx.x;
    for (int idx = t0; idx < 4*8*64*8; idx += 8*256) {       // W2: kt(4) x nt(8) x lane x 8
        int j = idx & 7, l = (idx >> 3) & 63, nt = (idx >> 9) & 7, kt = idx >> 12;
        int k = kt*32 + (l >> 4)*8 + j, n = nt*16 + (l & 15);
        Bsw[idx] = (_Float16)W2[k*HID + n];
    }
    for (int idx = t0; idx < 2*4*64*8; idx += 8*256) {       // protos: mt(2) x kt(4) x lane x 8
        int j = idx & 7, l = (idx >> 3) & 63, kt = (idx >> 9) & 3, mt = idx >> 11;
        int k = kt*32 + (l >> 4)*8 + j, mm = mt*16 + (l & 15);
        Asw[idx] = (mm < NN) ? (_Float16)protos[mm*HID + k] : (_Float16)0.0f;
    }
}

// ---------------- Kernel 1: ONE WAVE PER MATRIX, 2 waves/block, LDS-slim, barrier-free ---------
// History: R6 MFMA rewrite; R7 LDS union; R8 Sinkhorn fusion; R9 despill; R10 register Sinkhorn;
// R11 rcpf; R12 one-wave-per-matrix (409us @ occ 43.5%, LDS-capped); R13 slim-LDS 2-wave blocks
// -> allocator meltdown (FETCH 575MB/WRITE 511MB scratch; hoisted P2' loads + af+acc2+muv/rsv+bf
// all live under cap 84). R14 (this round): despill R13 keeping its structure:
// - muv/rsv -> sMurs LDS (64 f32/wave) after the stats reduce; fused loop re-reads 2 scalars/row.
// - chunk stores RAW f32 t = a[r]+b2v; LN2 applied AT READ: ((t-mu)*rs)*g2+bb then f16 cvt.
//   Same op order as before split across an exact f32 LDS hop -> bit-identical absmax.
// - asm memory fences stop the scheduler hoisting whole unrolled-loop load sets into one window.
// LDS ~10.8KB/block (14 blocks/CU); VGPR cap (128,6)~84, est peak ~80 -> 24 waves/CU (75%).
__global__ __launch_bounds__(128, 6) void k1_mlp(
    const float* __restrict__ A, const float* __restrict__ m,
    const float* __restrict__ tau_r,
    const float* __restrict__ ln1g, const float* __restrict__ ln1b,
    const float* __restrict__ W1, const float* __restrict__ b1,
    const float* __restrict__ b2,
    const float* __restrict__ ln2g, const float* __restrict__ ln2b,
    const _Float16* __restrict__ Bsw, const _Float16* __restrict__ Asw,
    float* __restrict__ out, int Btot)
{
    __shared__ __align__(16) float sU[2][32*CHF + 4];   // per-wave union: sA(729 f32) / chunkF
    __shared__ __align__(16) float sFeat2[2][132];      // 32 rows x 4 (pads zeroed)
    __shared__ __align__(16) float sMurs[2][64];        // {mu,rs} per H-row

    const int tid = threadIdx.x;
    const int w   = tid >> 6, l = tid & 63;
    const int b   = blockIdx.x * 2 + w;
    if (b >= Btot) return;                              // whole-wave exit; no block sync anywhere
    const int c = l & 15, g = l >> 4;

    float*    sA     = sU[w];
    float*    chunkF = sU[w];                           // aliases sA (dead after P1)
    float*    sFeat  = sFeat2[w];
    float*    murs   = sMurs[w];
    const float* Ab  = A + (size_t)b * (NN * NN);

    // ---- P0: stage A (per-wave) ----
    for (int i = l; i < NN * NN; i += 64) sA[i] = Ab[i];
    __builtin_amdgcn_wave_barrier();

    // ---- P1: features [log1p(rowsum), top1_offdiag, top2_offdiag, m] + LN1; zero pad rows ----
    if (l < NN) {
        const int n = l;
        float sum = 0.f, m1 = -1e30f, m2 = -1e30f;
        #pragma unroll
        for (int j = 0; j < NN; ++j) {
            float a = sA[n * NN + j];
            sum += a;
            float v = (j == n) ? 0.f : a;
            float nm1 = fmaxf(m1, v);
            m2 = fmaxf(m2, fminf(m1, v));
            m1 = nm1;
        }
        float f0 = log1pf(sum), f1 = m1, f2 = m2, f3 = m[(size_t)b * NN + n];
        float mu = 0.25f * (f0 + f1 + f2 + f3);
        float d0 = f0 - mu, d1 = f1 - mu, d2 = f2 - mu, d3 = f3 - mu;
        float var = 0.25f * (d0*d0 + d1*d1 + d2*d2 + d3*d3);
        float rs  = rsqrtf(var + 1e-5f);
        sFeat[n*4 + 0] = d0 * rs * ln1g[0] + ln1b[0];
        sFeat[n*4 + 1] = d1 * rs * ln1g[1] + ln1b[1];
        sFeat[n*4 + 2] = d2 * rs * ln1g[2] + ln1b[2];
        sFeat[n*4 + 3] = d3 * rs * ln1g[3] + ln1b[3];
    } else if (l < 32) {
        sFeat[l*4 + 0] = 0.f; sFeat[l*4 + 1] = 0.f;
        sFeat[l*4 + 2] = 0.f; sFeat[l*4 + 3] = 0.f;
    }
    __builtin_amdgcn_wave_barrier();

    // ---- P2': A-fragments of h1 DIRECTLY in registers (no LDS h1). Bit-exact FMA nesting:
    //      h = b1; h = fma(f3,w3,h); ...; h = fma(f0,w0,h); relu; cvt. Fences stop the
    //      scheduler hoisting all 4 kt iterations' W1/b1 loads at once (R13's meltdown). ----
    v4 fr0 = *(const v4*)&sFeat[(0*16 + c) * 4];
    v4 fr1 = *(const v4*)&sFeat[(1*16 + c) * 4];
    f16x8 af[2][4];
    #pragma unroll
    for (int kt = 0; kt < 4; ++kt) {
        asm volatile("" ::: "memory");                  // anti-hoist fence
        const int c0 = kt*32 + g*8;
        v4 bA = *(const v4*)&b1[c0];
        v4 bB = *(const v4*)&b1[c0 + 4];
        float h0[8], h1v[8];
        #pragma unroll
        for (int j = 0; j < 4; ++j) {
            h0[j] = bA[j];  h0[4+j] = bB[j];
            h1v[j] = bA[j]; h1v[4+j] = bB[j];
        }
        #pragma unroll
        for (int q = 3; q >= 0; --q) {
            v4 wA = *(const v4*)&W1[q*HID + c0];
            v4 wB = *(const v4*)&W1[q*HID + c0 + 4];
            float fq0 = fr0[q], fq1 = fr1[q];
            #pragma unroll
            for (int j = 0; j < 4; ++j) {
                h0[j]    = fmaf(fq0, wA[j], h0[j]);
                h0[4+j]  = fmaf(fq0, wB[j], h0[4+j]);
                h1v[j]   = fmaf(fq1, wA[j], h1v[j]);
                h1v[4+j] = fmaf(fq1, wB[j], h1v[4+j]);
            }
        }
        f16x8 v0, v1;
        #pragma unroll
        for (int j = 0; j < 8; ++j) {
            v0[j] = (_Float16)fmaxf(h0[j],  0.f);
            v1[j] = (_Float16)fmaxf(h1v[j], 0.f);
        }
        af[0][kt] = v0;
        af[1][kt] = v1;
    }

    // ---- P3 pass 1: GEMM2 LN2 stats only (tiles discarded); mu/rs parked in LDS after ----
    const f16x8* Bv = (const f16x8*)Bsw;
    float s4[2][4]  = {{0.f,0.f,0.f,0.f},{0.f,0.f,0.f,0.f}};
    float ss4[2][4] = {{0.f,0.f,0.f,0.f},{0.f,0.f,0.f,0.f}};
    #pragma unroll 1
    for (int nt = 0; nt < 8; ++nt) {
        asm volatile("" ::: "memory");                  // keep per-iter load set local
        f16x8 bf[4];
        #pragma unroll
        for (int kt = 0; kt < 4; ++kt) bf[kt] = Bv[(kt*8 + nt)*64 + l];
        float b2v = b2[nt*16 + c];
        #pragma unroll
        for (int mt = 0; mt < 2; ++mt) {
            v4 a = (v4)(0.f);
            #pragma unroll
            for (int kt = 0; kt < 4; ++kt)
                a = __builtin_amdgcn_mfma_f32_16x16x32_f16(af[mt][kt], bf[kt], a, 0, 0, 0);
            #pragma unroll
            for (int r = 0; r < 4; ++r) {
                float v = a[r] + b2v;
                s4[mt][r] += v; ss4[mt][r] += v * v;
            }
        }
    }
    {
        #pragma unroll
        for (int mt = 0; mt < 2; ++mt)
            #pragma unroll
            for (int r = 0; r < 4; ++r) {
                #pragma unroll
                for (int mask = 1; mask <= 8; mask <<= 1) {
                    s4[mt][r]  += __shfl_xor(s4[mt][r],  mask);
                    ss4[mt][r] += __shfl_xor(ss4[mt][r], mask);
                }
            }
        if (c == 0) {                                   // one lane per row-group parks mu/rs
            #pragma unroll
            for (int mt = 0; mt < 2; ++mt)
                #pragma unroll
                for (int r = 0; r < 4; ++r) {
                    float mu  = s4[mt][r] * (1.0f / HID);
                    float var = ss4[mt][r] * (1.0f / HID) - mu * mu;
                    int row = mt*16 + 4*g + r;
                    murs[2*row]     = mu;
                    murs[2*row + 1] = rsqrtf(var + 1e-5f);
                }
        }
    }
    __builtin_amdgcn_wave_barrier();

    // ---- P3 pass 2 FUSED with P5: per kt2 (k-cols kt2*32..+31 of H):
    //      recompute 2 nt-tiles -> store RAW t=a+b2v f32 -> read rows c,16+c applying
    //      LN2 (mu/rs from sMurs) + f16 cvt -> 4 score MFMA. chunkF aliases dead sA. ----
    const f16x8* Av = (const f16x8*)Asw;
    v4 acc2[2][2];
    acc2[0][0] = (v4)(0.f); acc2[0][1] = (v4)(0.f);
    acc2[1][0] = (v4)(0.f); acc2[1][1] = (v4)(0.f);
    #pragma unroll 1
    for (int kt2 = 0; kt2 < 4; ++kt2) {
        #pragma unroll
        for (int h = 0; h < 2; ++h) {
            asm volatile("" ::: "memory");              // anti-hoist fence
            int nt = kt2*2 + h;
            f16x8 bf[4];
            #pragma unroll
            for (int kt = 0; kt < 4; ++kt) bf[kt] = Bv[(kt*8 + nt)*64 + l];
            float b2v = b2[nt*16 + c];
            #pragma unroll
            for (int mt = 0; mt < 2; ++mt) {
                v4 a = (v4)(0.f);
                #pragma unroll
                for (int kt = 0; kt < 4; ++kt)
                    a = __builtin_amdgcn_mfma_f32_16x16x32_f16(af[mt][kt], bf[kt], a, 0, 0, 0);
                #pragma unroll
                for (int r = 0; r < 4; ++r)
                    chunkF[(mt*16 + 4*g + r) * CHF + h*16 + c] = a[r] + b2v;
            }
        }
        __builtin_amdgcn_wave_barrier();                // chunk writes ordered before reads

        f16x8 bfr[2];
        #pragma unroll
        for (int half = 0; half < 2; ++half) {
            asm volatile("" ::: "memory");              // stage coefs per half only
            const int row = half*16 + c;
            const int k0  = kt2*32 + g*8;
            v4 raA = *(const v4*)&chunkF[row*CHF + g*8];
            v4 raB = *(const v4*)&chunkF[row*CHF + g*8 + 4];
            float mu = murs[2*row], rs = murs[2*row + 1];
            v4 g2A = *(const v4*)&ln2g[k0], g2B = *(const v4*)&ln2g[k0 + 4];
            v4 bbA = *(const v4*)&ln2b[k0], bbB = *(const v4*)&ln2b[k0 + 4];
            f16x8 bb;
            #pragma unroll
            for (int j = 0; j < 4; ++j) {
                bb[j]     = (_Float16)(((raA[j] - mu) * rs) * g2A[j] + bbA[j]);
                bb[4 + j] = (_Float16)(((raB[j] - mu) * rs) * g2B[j] + bbB[j]);
            }
            bfr[half] = bb;
        }
        f16x8 pa0 = Av[(0*4 + kt2)*64 + l];
        f16x8 pa1 = Av[(1*4 + kt2)*64 + l];
        acc2[0][0] = __builtin_amdgcn_mfma_f32_16x16x32_f16(pa0, bfr[0], acc2[0][0], 0, 0, 0);
        acc2[0][1] = __builtin_amdgcn_mfma_f32_16x16x32_f16(pa0, bfr[1], acc2[0][1], 0, 0, 0);
        acc2[1][0] = __builtin_amdgcn_mfma_f32_16x16x32_f16(pa1, bfr[0], acc2[1][0], 0, 0, 0);
        acc2[1][1] = __builtin_amdgcn_mfma_f32_16x16x32_f16(pa1, bfr[1], acc2[1][1], 0, 0, 0);
        __builtin_amdgcn_wave_barrier();                // reads ordered before next iter writes
    }

    // ---- P6: P = exp(score/tau) in registers. i = mt*16+4g+r, j0 = c, j1 = 16+c ----
    float p[2][2][4];
    float rowm1[4], rowp1[4];
    #pragma unroll
    for (int r = 0; r < 4; ++r) {
        rowm1[r] = ((16 + 4*g + r) < NN) ? 1.f : 0.f;
        rowp1[r] = 1.f - rowm1[r];
    }
    const float colm1 = ((16 + c) < NN) ? 1.f : 0.f;
    const float colp1 = 1.f - colm1;
    {
        const float inv_tau = 1.0f / tau_r[0];
        #pragma unroll
        for (int r = 0; r < 4; ++r) {
            p[0][0][r] = __expf(acc2[0][0][r] * inv_tau);
            p[0][1][r] = (colm1 != 0.f) ? __expf(acc2[0][1][r] * inv_tau) : 0.f;
            bool iok = (16 + 4*g + r) < NN;
            p[1][0][r] = iok ? __expf(acc2[1][0][r] * inv_tau) : 0.f;
            p[1][1][r] = (iok && colm1 != 0.f) ? __expf(acc2[1][1][r] * inv_tau) : 0.f;
        }
    }

    // ---- P7: 20-iter Sinkhorn, fully wave-local (shfl + rcpf only; no LDS, no barriers) ----
    for (int it = 0; it < SITERS; ++it) {
        #pragma unroll
        for (int r = 0; r < 4; ++r) {           // row normalize, mt=0 (always valid)
            float s = p[0][0][r] + p[0][1][r];
            s += __shfl_xor(s, 1);
            s += __shfl_xor(s, 2);
            s += __shfl_xor(s, 4);
            s += __shfl_xor(s, 8);
            float rho = __builtin_amdgcn_rcpf(s);
            p[0][0][r] *= rho;
            p[0][1][r] *= rho;
        }
        #pragma unroll
        for (int r = 0; r < 4; ++r) {           // row normalize, mt=1 (pad rows stay exact 0)
            float s = p[1][0][r] + p[1][1][r];
            s += __shfl_xor(s, 1);
            s += __shfl_xor(s, 2);
            s += __shfl_xor(s, 4);
            s += __shfl_xor(s, 8);
            float rho = __builtin_amdgcn_rcpf(s + rowp1[r]) * rowm1[r];
            p[1][0][r] *= rho;
            p[1][1][r] *= rho;
        }
        // col normalize: sum over (mt,r) in-thread, then g-groups via shfl 16/32
        float t0 = ((p[0][0][0] + p[0][0][1]) + (p[0][0][2] + p[0][0][3]))
                 + ((p[1][0][0] + p[1][0][1]) + (p[1][0][2] + p[1][0][3]));
        float t1 = ((p[0][1][0] + p[0][1][1]) + (p[0][1][2] + p[0][1][3]))
                 + ((p[1][1][0] + p[1][1][1]) + (p[1][1][2] + p[1][1][3]));
        t0 += __shfl_xor(t0, 16);  t0 += __shfl_xor(t0, 32);
        t1 += __shfl_xor(t1, 16);  t1 += __shfl_xor(t1, 32);
        float rc0 = __builtin_amdgcn_rcpf(t0);
        float rc1 = __builtin_amdgcn_rcpf(t1 + colp1) * colm1;
        #pragma unroll
        for (int mt = 0; mt < 2; ++mt) {
            #pragma unroll
            for (int r = 0; r < 4; ++r) {
                p[mt][0][r] *= rc0;
                p[mt][1][r] *= rc1;
            }
        }
    }

    // ---- P8: store P straight from registers (16-lane contiguous runs) ----
    {
        float* ob = out + (size_t)b * (NN * NN);
        #pragma unroll
        for (int r = 0; r < 4; ++r) {
            int i = 4*g + r;
            ob[i * NN + c] = p[0][0][r];
            if ((16 + c) < NN) ob[i * NN + 16 + c] = p[0][1][r];
        }
        #pragma unroll
        for (int r = 0; r < 4; ++r) {
            int i = 16 + 4*g + r;
            if (i < NN) {
                ob[i * NN + c] = p[1][0][r];
                if ((16 + c) < NN) ob[i * NN + 16 + c] = p[1][1][r];
            }
        }
    }
}

extern "C" void kernel_launch(void* const* d_in, const int* in_sizes, int n_in,
                              void* d_out, int out_size, void* d_ws, size_t ws_size,
                              hipStream_t stream) {
    const float* A      = (const float*)d_in[0];
    const float* m      = (const float*)d_in[1];
    const float* tau_r  = (const float*)d_in[2];
    const float* ln1g   = (const float*)d_in[3];
    const float* ln1b   = (const float*)d_in[4];
    const float* W1     = (const float*)d_in[5];
    const float* b1     = (const float*)d_in[6];
    const float* W2     = (const float*)d_in[7];
    const float* b2     = (const float*)d_in[8];
    const float* ln2g   = (const float*)d_in[9];
    const float* ln2b   = (const float*)d_in[10];
    const float* protos = (const float*)d_in[11];
    float* out = (float*)d_out;

    const int B = in_sizes[0] / (NN * NN);

    _Float16* Bsw = (_Float16*)d_ws;                         // 16384 f16 = 32 KB
    _Float16* Asw = (_Float16*)((char*)d_ws + 32768);        //  4096 f16 =  8 KB

    k0_prep<<<8, 256, 0, stream>>>(W2, protos, Bsw, Asw);
    const int blocks1 = (B + 1) / 2;
    k1_mlp<<<blocks1, 128, 0, stream>>>(A, m, tau_r, ln1g, ln1b, W1, b1, b2,
                                        ln2g, ln2b, Bsw, Asw, out, B);
}